// Round 1
// baseline (160.981 us; speedup 1.0000x reference)
//
#include <hip/hip_runtime.h>
#include <hip/hip_bf16.h>

typedef unsigned short u16;
typedef unsigned int   u32;
typedef __attribute__((ext_vector_type(8))) short  bf16x8;
typedef __attribute__((ext_vector_type(4))) float  floatx4;

#define NB 2
#define NT 4
#define CK 64
#define CV 256
#define HH 64
#define WW 64
#define MM 4096    // NT*32*32
#define NN 4096    // HH*WW
#define SCALE 0.125f
#define SHIFT 4.0f
#define OUT_B 2097152      // f32 elems per batch in out (512*4096)
#define NW 32              // n-columns per attn block
#define NIT 32             // MM / 128

__device__ __forceinline__ u16 f2b(float f) {
    __hip_bfloat16 h = __float2bfloat16(f);
    union { __hip_bfloat16 h; u16 u; } v; v.h = h; return v.u;
}

// ============================ fast (MFMA) path ============================
// prep: K -> pk2[b][cblk(8)][m(4096)][8c]  (fragment-tiled, 16B stores)
//       V -> vt[b][c][m]                    (8B ushort4 stores)
//       qv -> out[:, 0:256, :, :]           (float4 copy)
#define PRE_K 65536        // NB*8*4096
#define PRE_V 589824       // + NB*CV*MM/4 (=524288)
#define PRE_T 1114112      // + NB*CV*HH*WW/4 (=524288)

__global__ void prep(const float* __restrict__ mk, const float* __restrict__ mv,
                     const float4* __restrict__ qv,
                     u16* __restrict__ pk2, u16* __restrict__ vt,
                     float* __restrict__ out) {
    int u = blockIdx.x * 256 + threadIdx.x;
    if (u < PRE_K) {
        // one thread = 8 c-values at one m -> coalesced float2 reads, 16B write
        int m = u & 4095, cb8 = (u >> 12) & 7, b = u >> 15;
        int t = m >> 10, hh = (m >> 5) & 31, ww = m & 31;
        const float* s0 = mk + ((size_t)((b*NT + t)*CK + cb8*8))*(HH*WW)
                             + (2*hh)*WW + 2*ww;
        bf16x8 fr;
        #pragma unroll
        for (int i = 0; i < 8; ++i) {
            const float* s = s0 + (size_t)i*(HH*WW);
            float2 r0 = *(const float2*)s;
            float2 r1 = *(const float2*)(s + WW);
            fr[i] = (short)f2b(fmaxf(fmaxf(r0.x, r0.y), fmaxf(r1.x, r1.y)));
        }
        *(bf16x8*)(pk2 + ((size_t)(b*8 + cb8)*MM + m)*8) = fr;
    } else if (u < PRE_V) {
        // one thread = 4 consecutive m at one c -> float4 reads, 8B write
        int u2 = u - PRE_K;
        int m4 = u2 & 1023, c = (u2 >> 10) & 255, b = u2 >> 18;
        int t = m4 >> 8, hh = (m4 >> 3) & 31, w8 = m4 & 7;
        const float* s0 = mv + ((size_t)((b*NT + t)*CV + c))*(HH*WW)
                             + (2*hh)*WW + 8*w8;
        float4 a0 = *(const float4*)(s0);
        float4 a1 = *(const float4*)(s0 + 4);
        float4 b0 = *(const float4*)(s0 + WW);
        float4 b1 = *(const float4*)(s0 + WW + 4);
        ushort4 r;
        r.x = f2b(fmaxf(fmaxf(a0.x, a0.y), fmaxf(b0.x, b0.y)));
        r.y = f2b(fmaxf(fmaxf(a0.z, a0.w), fmaxf(b0.z, b0.w)));
        r.z = f2b(fmaxf(fmaxf(a1.x, a1.y), fmaxf(b1.x, b1.y)));
        r.w = f2b(fmaxf(fmaxf(a1.z, a1.w), fmaxf(b1.z, b1.w)));
        *(ushort4*)(vt + ((size_t)(b*CV + c)*MM) + m4*4) = r;
    } else {
        int u3 = u - PRE_V;
        int b = u3 >> 18, ru = u3 & 262143;
        ((float4*)out)[(size_t)b*(OUT_B/4) + ru] = qv[u3];
    }
}

// ---- attn phases (layouts identical to the proven round-5 kernel) ----
__device__ __forceinline__ void qk_phase(bf16x8 k0, bf16x8 k1,
        const bf16x8 (&qf)[2][2], float (&sacc)[2],
        u16* __restrict__ Pd, int lrow, int cbw, int sw)
{
    #pragma unroll
    for (int t = 0; t < 2; ++t) {
        floatx4 s = __builtin_amdgcn_mfma_f32_16x16x32_bf16(
                        k0, qf[0][t], (floatx4){0.f,0.f,0.f,0.f}, 0, 0, 0);
        s = __builtin_amdgcn_mfma_f32_16x16x32_bf16(k1, qf[1][t], s, 0, 0, 0);
        // C layout: n_l = t*16+lrow, m_l = 16w + quad*4 + r
        float p0 = __expf(s[0]*SCALE - SHIFT);
        float p1 = __expf(s[1]*SCALE - SHIFT);
        float p2 = __expf(s[2]*SCALE - SHIFT);
        float p3 = __expf(s[3]*SCALE - SHIFT);
        sacc[t] += (p0 + p1) + (p2 + p3);
        u32 d0 = (u32)f2b(p0) | ((u32)f2b(p1) << 16);
        u32 d1 = (u32)f2b(p2) | ((u32)f2b(p3) << 16);
        *(uint2*)&Pd[(t*16 + lrow)*128 + ((cbw ^ sw) << 2)] = make_uint2(d0, d1);
    }
}

__device__ __forceinline__ void pv_phase(const bf16x8 (&vf)[4][2],
        floatx4 (&oacc)[2][2], const u16* __restrict__ Ps,
        int lrow, int quad, int sw)
{
    #pragma unroll
    for (int cc = 0; cc < 4; ++cc) {
        bf16x8 pf[2];
        #pragma unroll
        for (int t = 0; t < 2; ++t) {
            int cb = (cc << 3) + (quad << 1);
            pf[t] = *(const bf16x8*)&Ps[(t*16 + lrow)*128 + ((cb ^ sw) << 2)];
        }
        __builtin_amdgcn_s_setprio(1);
        #pragma unroll
        for (int j = 0; j < 2; ++j)
            #pragma unroll
            for (int t = 0; t < 2; ++t)
                oacc[j][t] = __builtin_amdgcn_mfma_f32_16x16x32_bf16(
                                 vf[cc][j], pf[t], oacc[j][t], 0, 0, 0);
        __builtin_amdgcn_s_setprio(0);
    }
}

// Full-M attention: grid 256 (= 128 ntiles x 2 b, XCD-chunked), 512 thr = 8 waves.
// Per iter (128 m): QK: wave w owns m rows [16w,16w+16); PV: c in [32w,32w+32).
// Single barrier/iter via P double-buffer; k/v for it+1 prefetched post-barrier.
// Softmax denom reduced in-block; normalized output written directly (no part).
__launch_bounds__(512, 2)
__global__ void attn_v2(const u16* __restrict__ pk2, const u16* __restrict__ vt,
                        const float* __restrict__ qk, float* __restrict__ out) {
    const int bid = blockIdx.x;
    const int xcd = bid & 7;                      // presumed bid%8 -> XCD
    const int b   = xcd >> 2;                     // one b per XCD: vt slice L2-fits
    const int ntile = ((bid >> 3) << 2) + (xcd & 3);
    const int tid = threadIdx.x, w = tid >> 6, l = tid & 63;
    const int lrow = l & 15, quad = l >> 4;
    const int n0 = ntile * NW;
    const int sw = lrow << 1;                     // XOR swizzle key (keeps 16B pairs)
    const int cbw = (w << 2) + quad;              // QK write chunk = m_l>>2

    __shared__ u16  P[2][NW * 128];               // 2 x 8 KB, row=n_l (256 B)
    __shared__ float sums_s[8][NW];

    // Q B-fragments: B[k=c][n]: n = n0+t*16+lrow, c = cc*32+quad*8+i
    bf16x8 qf[2][2];
    const float* qb = qk + (size_t)b * CK * NN + n0;
    #pragma unroll
    for (int cc = 0; cc < 2; ++cc)
        #pragma unroll
        for (int t = 0; t < 2; ++t)
            #pragma unroll
            for (int i = 0; i < 8; ++i) {
                int c = cc*32 + quad*8 + i;
                qf[cc][t][i] = (short)f2b(qb[(size_t)c*NN + t*16 + lrow]);
            }

    const u16* pkb  = pk2 + (size_t)b * (8*MM*8);
    const u16* vtb  = vt  + (size_t)b * CV * MM;
    const int  mrw  = w*16 + lrow;                // K A-frag row offset
    const u16* vrow = vtb + (size_t)(w*32 + lrow)*MM + quad*8;

    floatx4 oacc[2][2];
    #pragma unroll
    for (int j = 0; j < 2; ++j)
        #pragma unroll
        for (int t = 0; t < 2; ++t)
            oacc[j][t] = (floatx4){0.f, 0.f, 0.f, 0.f};
    float sacc[2] = {0.f, 0.f};

    // ---- preamble: loads for iter 0, QK(0) -> P[0]
    bf16x8 vf[4][2];
    {
        bf16x8 k0 = *(const bf16x8*)(pkb + ((size_t)quad*MM + mrw)*8);
        bf16x8 k1 = *(const bf16x8*)(pkb + ((size_t)(quad+4)*MM + mrw)*8);
        #pragma unroll
        for (int cc = 0; cc < 4; ++cc)
            #pragma unroll
            for (int j = 0; j < 2; ++j)
                vf[cc][j] = *(const bf16x8*)(vrow + (size_t)j*(16*MM) + cc*32);
        qk_phase(k0, k1, qf, sacc, P[0], lrow, cbw, sw);
    }

    #pragma unroll 2
    for (int it = 0; it < NIT; ++it) {
        __syncthreads();                          // P[it&1] complete
        const bool more = (it + 1 < NIT);
        bf16x8 k0n, k1n, vfn[4][2];
        if (more) {                               // prefetch it+1 (post-barrier:
            const int mb2 = (it + 1) << 7;        //  latency hides under PV)
            k0n = *(const bf16x8*)(pkb + ((size_t)quad*MM + mb2 + mrw)*8);
            k1n = *(const bf16x8*)(pkb + ((size_t)(quad+4)*MM + mb2 + mrw)*8);
            #pragma unroll
            for (int cc = 0; cc < 4; ++cc)
                #pragma unroll
                for (int j = 0; j < 2; ++j)
                    vfn[cc][j] = *(const bf16x8*)(vrow + (size_t)j*(16*MM) + mb2 + cc*32);
        }
        pv_phase(vf, oacc, P[it & 1], lrow, quad, sw);
        if (more) {
            qk_phase(k0n, k1n, qf, sacc, P[(it + 1) & 1], lrow, cbw, sw);
            #pragma unroll
            for (int cc = 0; cc < 4; ++cc)
                #pragma unroll
                for (int j = 0; j < 2; ++j)
                    vf[cc][j] = vfn[cc][j];
        }
    }

    // ---- softmax denominator: quad-reduce, then 8-wave LDS reduce
    #pragma unroll
    for (int t = 0; t < 2; ++t) {
        float v = sacc[t];
        v += __shfl_xor(v, 16, 64);
        v += __shfl_xor(v, 32, 64);
        if (l < 16) sums_s[w][t*16 + l] = v;
    }
    __syncthreads();
    float inv[2];
    #pragma unroll
    for (int t = 0; t < 2; ++t) {
        float d = 0.f;
        #pragma unroll
        for (int w2 = 0; w2 < 8; ++w2) d += sums_s[w2][t*16 + lrow];
        inv[t] = 1.0f / d;
    }

    // ---- normalized direct write: out[b, 256+c, n0+n_l]
    float* ob = out + ((size_t)(b*512 + 256))*NN + n0;
    #pragma unroll
    for (int j = 0; j < 2; ++j)
        #pragma unroll
        for (int t = 0; t < 2; ++t)
            #pragma unroll
            for (int r = 0; r < 4; ++r) {
                int c = w*32 + j*16 + quad*4 + r;
                ob[(size_t)c*NN + t*16 + lrow] = oacc[j][t][r] * inv[t];
            }
}

// ======================= fallback (proven round-4) path =======================

__global__ void pool_v_f32(const float* __restrict__ src, float* __restrict__ out) {
    int e = blockIdx.x * 256 + threadIdx.x;
    int c = e & 255;
    int r = e >> 8;
    int ww = r & 31;  int hh = (r >> 5) & 31;
    int t  = (r >> 10) & 3;  int b = r >> 12;
    int m  = r & (MM - 1);
    const float* s = src + ((size_t)(((b*NT + t)*CV + c)*HH + 2*hh))*WW + 2*ww;
    out[(size_t)b*OUT_B + (size_t)m*CV + c] = fmaxf(fmaxf(s[0], s[1]), fmaxf(s[WW], s[WW+1]));
}

__global__ void pool_k_f32(const float* __restrict__ src, float* __restrict__ dst) {
    int e = blockIdx.x * 256 + threadIdx.x;
    int c = e & 63;
    int r = e >> 6;
    int ww = r & 31;  int hh = (r >> 5) & 31;
    int t  = (r >> 10) & 3;  int b = r >> 12;
    const float* s = src + ((size_t)(((b*NT + t)*CK + c)*HH + 2*hh))*WW + 2*ww;
    dst[e] = fmaxf(fmaxf(s[0], s[1]), fmaxf(s[WW], s[WW+1]));
}

__global__ void copy_qv_f32(const float4* __restrict__ src, float4* __restrict__ dst) {
    int u = blockIdx.x * 256 + threadIdx.x;
    int b  = u >> 18;
    int ru = u & 262143;
    dst[(size_t)b * (OUT_B/4) + ru] = src[u];
}

template<bool STAGED_K>
__launch_bounds__(256)
__global__ void attn_old(const float* __restrict__ pk,
                         const float* __restrict__ mk,
                         const float* __restrict__ qk,
                         float* __restrict__ out) {
    __shared__ __align__(16) float q_lds[CK][4];
    __shared__ __align__(16) float sarr[4][MM];
    __shared__ float inv_l[4];

    const int tid = threadIdx.x;
    const int blk = blockIdx.x;
    const int b   = blk >> 10;
    const int n0  = (blk & 1023) << 2;

    {
        int c = tid >> 2, qi = tid & 3;
        q_lds[c][qi] = qk[((size_t)(b*CK + c))*NN + n0 + qi];
    }
    __syncthreads();

    #pragma unroll
    for (int i = 0; i < 16; ++i) {
        int m = tid + (i << 8);
        float a0 = 0.f, a1 = 0.f, a2 = 0.f, a3 = 0.f;
        if (STAGED_K) {
            const float4* k4 = reinterpret_cast<const float4*>(pk + ((size_t)b*MM + m)*CK);
            #pragma unroll
            for (int cc = 0; cc < 16; ++cc) {
                float4 kv = k4[cc];
                int c = cc*4;
                float4 q0 = *reinterpret_cast<const float4*>(&q_lds[c][0]);
                float4 q1 = *reinterpret_cast<const float4*>(&q_lds[c+1][0]);
                float4 q2 = *reinterpret_cast<const float4*>(&q_lds[c+2][0]);
                float4 q3 = *reinterpret_cast<const float4*>(&q_lds[c+3][0]);
                a0 += kv.x*q0.x + kv.y*q1.x + kv.z*q2.x + kv.w*q3.x;
                a1 += kv.x*q0.y + kv.y*q1.y + kv.z*q2.y + kv.w*q3.y;
                a2 += kv.x*q0.z + kv.y*q1.z + kv.z*q2.z + kv.w*q3.z;
                a3 += kv.x*q0.w + kv.y*q1.w + kv.z*q2.w + kv.w*q3.w;
            }
        } else {
            int ww = m & 31, hh = (m >> 5) & 31, t = m >> 10;
            const float* base = mk + ((size_t)((b*NT + t)*CK)*HH + 2*hh)*WW + 2*ww;
            for (int c = 0; c < CK; ++c) {
                const float* s = base + (size_t)c*HH*WW;
                float kv = fmaxf(fmaxf(s[0], s[1]), fmaxf(s[WW], s[WW+1]));
                float4 q = *reinterpret_cast<const float4*>(&q_lds[c][0]);
                a0 += kv*q.x; a1 += kv*q.y; a2 += kv*q.z; a3 += kv*q.w;
            }
        }
        sarr[0][m] = a0*SCALE;
        sarr[1][m] = a1*SCALE;
        sarr[2][m] = a2*SCALE;
        sarr[3][m] = a3*SCALE;
    }
    __syncthreads();

    const int wave = tid >> 6, lane = tid & 63;
    float mx = -3.0e38f;
    for (int m = lane; m < MM; m += 64) mx = fmaxf(mx, sarr[wave][m]);
    #pragma unroll
    for (int off = 32; off > 0; off >>= 1) mx = fmaxf(mx, __shfl_xor(mx, off, 64));
    float ls = 0.f;
    for (int m = lane; m < MM; m += 64) {
        float p = __expf(sarr[wave][m] - mx);
        sarr[wave][m] = p;
        ls += p;
    }
    #pragma unroll
    for (int off = 32; off > 0; off >>= 1) ls += __shfl_xor(ls, off, 64);
    if (lane == 0) inv_l[wave] = 1.0f / ls;
    __syncthreads();

    const int c4 = lane;
    const float4* vb = reinterpret_cast<const float4*>(out + (size_t)b*OUT_B) + c4;
    const float* prow = sarr[wave];
    float a0 = 0.f, a1 = 0.f, a2 = 0.f, a3 = 0.f;
    for (int m = 0; m < MM; m += 4) {
        float4 p4 = *reinterpret_cast<const float4*>(prow + m);
        const float4* vp = vb + (size_t)m*(CV/4);
        float4 v0 = vp[0], v1 = vp[CV/4], v2 = vp[CV/2], v3 = vp[3*(CV/4)];
        a0 += p4.x*v0.x + p4.y*v1.x + p4.z*v2.x + p4.w*v3.x;
        a1 += p4.x*v0.y + p4.y*v1.y + p4.z*v2.y + p4.w*v3.y;
        a2 += p4.x*v0.z + p4.y*v1.z + p4.z*v2.z + p4.w*v3.z;
        a3 += p4.x*v0.w + p4.y*v1.w + p4.z*v2.w + p4.w*v3.w;
    }

    float inv = inv_l[wave];
    int n = n0 + wave;
    size_t ob = ((size_t)(b*512 + 256 + c4*4))*NN + n;
    out[ob]        = a0*inv;
    out[ob + NN]   = a1*inv;
    out[ob + 2*NN] = a2*inv;
    out[ob + 3*NN] = a3*inv;
}

// ================================ launcher ================================

extern "C" void kernel_launch(void* const* d_in, const int* in_sizes, int n_in,
                              void* d_out, int out_size, void* d_ws, size_t ws_size,
                              hipStream_t stream) {
    const float* mk = (const float*)d_in[0];
    const float* mv = (const float*)d_in[1];
    const float* qk = (const float*)d_in[2];
    const float* qv = (const float*)d_in[3];
    float* out = (float*)d_out;

    // fast-path ws layout: pk2 1MB | vt 4MB  (5 MB total)
    u16* pk2 = (u16*)d_ws;
    u16* vt  = pk2 + (size_t)NB*8*MM*8;                 // 524288 u16
    const size_t need = ((size_t)NB*8*MM*8 + (size_t)NB*CV*MM) * sizeof(u16);

    if (ws_size >= need) {
        prep<<<PRE_T/256, 256, 0, stream>>>(mk, mv, (const float4*)qv, pk2, vt, out);
        attn_v2<<<256, 512, 0, stream>>>(pk2, vt, qk, out);
    } else {
        const size_t pk_bytes = (size_t)NB*MM*CK*sizeof(float);
        const bool staged = (ws_size >= pk_bytes);
        float* pk = (float*)d_ws;
        pool_v_f32<<<(NB*MM*CV)/256, 256, 0, stream>>>(mv, out);
        if (staged) {
            pool_k_f32<<<(NB*MM*CK)/256, 256, 0, stream>>>(mk, pk);
            attn_old<true ><<<NB*(NN/4), 256, 0, stream>>>(pk, mk, qk, out);
        } else {
            attn_old<false><<<NB*(NN/4), 256, 0, stream>>>(pk, mk, qk, out);
        }
        copy_qv_f32<<<((NB*CV*HH*WW)/4)/256, 256, 0, stream>>>((const float4*)qv, (float4*)out);
    }
}

// Round 2
// 143.723 us; speedup vs baseline: 1.1201x; 1.1201x over previous
//
#include <hip/hip_runtime.h>
#include <hip/hip_bf16.h>

typedef unsigned short u16;
typedef unsigned int   u32;
typedef __attribute__((ext_vector_type(8))) short  bf16x8;
typedef __attribute__((ext_vector_type(4))) float  floatx4;

#define NB 2
#define NT 4
#define CK 64
#define CV 256
#define HH 64
#define WW 64
#define MM 4096    // NT*32*32
#define NN 4096    // HH*WW
#define SCALE 0.125f
#define SHIFT 4.0f
#define OUT_B 2097152      // f32 elems per batch in out (512*4096)
#define NW 64              // n-columns per attn block
#define NIT 32             // MM / 128

__device__ __forceinline__ u16 f2b(float f) {
    __hip_bfloat16 h = __float2bfloat16(f);
    union { __hip_bfloat16 h; u16 u; } v; v.h = h; return v.u;
}

// ============================ fast (MFMA) path ============================
// prep: K -> pk2[b][cblk(8)][m(4096)][8c]  (fragment-tiled, 16B stores)
//       V -> vt[b][c][m]                    (8B ushort4 stores)
//       qv -> out[:, 0:256, :, :]           (float4 copy)
#define PRE_K 65536        // NB*8*4096
#define PRE_V 589824       // + NB*CV*MM/4 (=524288)
#define PRE_T 1114112      // + NB*CV*HH*WW/4 (=524288)

__global__ void prep(const float* __restrict__ mk, const float* __restrict__ mv,
                     const float4* __restrict__ qv,
                     u16* __restrict__ pk2, u16* __restrict__ vt,
                     float* __restrict__ out) {
    int u = blockIdx.x * 256 + threadIdx.x;
    if (u < PRE_K) {
        // one thread = 8 c-values at one m -> coalesced float2 reads, 16B write
        int m = u & 4095, cb8 = (u >> 12) & 7, b = u >> 15;
        int t = m >> 10, hh = (m >> 5) & 31, ww = m & 31;
        const float* s0 = mk + ((size_t)((b*NT + t)*CK + cb8*8))*(HH*WW)
                             + (2*hh)*WW + 2*ww;
        bf16x8 fr;
        #pragma unroll
        for (int i = 0; i < 8; ++i) {
            const float* s = s0 + (size_t)i*(HH*WW);
            float2 r0 = *(const float2*)s;
            float2 r1 = *(const float2*)(s + WW);
            fr[i] = (short)f2b(fmaxf(fmaxf(r0.x, r0.y), fmaxf(r1.x, r1.y)));
        }
        *(bf16x8*)(pk2 + ((size_t)(b*8 + cb8)*MM + m)*8) = fr;
    } else if (u < PRE_V) {
        // one thread = 4 consecutive m at one c -> float4 reads, 8B write
        int u2 = u - PRE_K;
        int m4 = u2 & 1023, c = (u2 >> 10) & 255, b = u2 >> 18;
        int t = m4 >> 8, hh = (m4 >> 3) & 31, w8 = m4 & 7;
        const float* s0 = mv + ((size_t)((b*NT + t)*CV + c))*(HH*WW)
                             + (2*hh)*WW + 8*w8;
        float4 a0 = *(const float4*)(s0);
        float4 a1 = *(const float4*)(s0 + 4);
        float4 b0 = *(const float4*)(s0 + WW);
        float4 b1 = *(const float4*)(s0 + WW + 4);
        ushort4 r;
        r.x = f2b(fmaxf(fmaxf(a0.x, a0.y), fmaxf(b0.x, b0.y)));
        r.y = f2b(fmaxf(fmaxf(a0.z, a0.w), fmaxf(b0.z, b0.w)));
        r.z = f2b(fmaxf(fmaxf(a1.x, a1.y), fmaxf(b1.x, b1.y)));
        r.w = f2b(fmaxf(fmaxf(a1.z, a1.w), fmaxf(b1.z, b1.w)));
        *(ushort4*)(vt + ((size_t)(b*CV + c)*MM) + m4*4) = r;
    } else {
        int u3 = u - PRE_V;
        int b = u3 >> 18, ru = u3 & 262143;
        ((float4*)out)[(size_t)b*(OUT_B/4) + ru] = qv[u3];
    }
}

// ---- attn phases ----
// QK: wave w owns m-rows [16w,16w+16) of the 128-m iter, all 64 n.
// S C-layout: n_l = t*16+lrow, m_l = 16w + quad*4 + r.
__device__ __forceinline__ void qk_phase(bf16x8 k0, bf16x8 k1,
        const bf16x8 (&qf)[2][4], float (&sacc)[4],
        u16* __restrict__ Pd, int lrow, int cbw, int sw)
{
    #pragma unroll
    for (int t = 0; t < 4; ++t) {
        floatx4 s = __builtin_amdgcn_mfma_f32_16x16x32_bf16(
                        k0, qf[0][t], (floatx4){0.f,0.f,0.f,0.f}, 0, 0, 0);
        s = __builtin_amdgcn_mfma_f32_16x16x32_bf16(k1, qf[1][t], s, 0, 0, 0);
        float p0 = __expf(s[0]*SCALE - SHIFT);
        float p1 = __expf(s[1]*SCALE - SHIFT);
        float p2 = __expf(s[2]*SCALE - SHIFT);
        float p3 = __expf(s[3]*SCALE - SHIFT);
        sacc[t] += (p0 + p1) + (p2 + p3);
        u32 d0 = (u32)f2b(p0) | ((u32)f2b(p1) << 16);
        u32 d1 = (u32)f2b(p2) | ((u32)f2b(p3) << 16);
        *(uint2*)&Pd[(t*16 + lrow)*128 + ((cbw ^ sw) << 2)] = make_uint2(d0, d1);
    }
}

// PV: wave w owns c-rows [16w,16w+16) of the block's 128-c half, all 64 n.
__device__ __forceinline__ void pv_phase(const bf16x8 (&vf)[4],
        floatx4 (&oacc)[4], const u16* __restrict__ Ps,
        int lrow, int quad, int sw)
{
    #pragma unroll
    for (int cc = 0; cc < 4; ++cc) {
        bf16x8 pf[4];
        #pragma unroll
        for (int t = 0; t < 4; ++t) {
            int cb = (cc << 3) + (quad << 1);
            pf[t] = *(const bf16x8*)&Ps[(t*16 + lrow)*128 + ((cb ^ sw) << 2)];
        }
        __builtin_amdgcn_s_setprio(1);
        #pragma unroll
        for (int t = 0; t < 4; ++t)
            oacc[t] = __builtin_amdgcn_mfma_f32_16x16x32_bf16(
                          vf[cc], pf[t], oacc[t], 0, 0, 0);
        __builtin_amdgcn_s_setprio(0);
    }
}

// Full-M attention, c-split PV: grid 256 = 64 ntiles x 2 b x 2 csplit.
// 512 threads = 8 waves. QK duplicated across csplit (1/5 of FLOPs) so the
// softmax denominator is block-local -> direct normalized write, no epilogue.
// P double-buffered in LDS: ONE barrier/iter; next-iter K/V loads issued
// unconditionally right after the barrier (loop peeled - nothing for the
// compiler to sink behind), consumed after PV.
__launch_bounds__(512, 2)
__global__ void attn_v3(const u16* __restrict__ pk2, const u16* __restrict__ vt,
                        const float* __restrict__ qk, float* __restrict__ out) {
    const int bid = blockIdx.x;
    const int xcd = bid & 7, grp = bid >> 3;        // presumed bid%8 -> XCD
    const int b   = xcd >> 2, cs = (xcd >> 1) & 1;  // XCD's 1.5 MB K+V slice L2-fits
    const int ntile = (xcd & 1) * 32 + grp;
    const int tid = threadIdx.x, w = tid >> 6, l = tid & 63;
    const int lrow = l & 15, quad = l >> 4;
    const int n0 = ntile * NW;
    const int sw  = lrow << 1;                      // XOR swizzle (keeps 16B pairs)
    const int cbw = (w << 2) + quad;                // QK write chunk = m_l>>2

    __shared__ u16  P[2][NW * 128];                 // 2 x 16 KB, row=n_l (256 B)
    __shared__ float sums_s[8][NW];

    // Q B-fragments: B[k=c][n]: n = n0+t*16+lrow, c = cc*32+quad*8+i
    bf16x8 qf[2][4];
    const float* qb = qk + (size_t)b * CK * NN + n0;
    #pragma unroll
    for (int cc = 0; cc < 2; ++cc)
        #pragma unroll
        for (int t = 0; t < 4; ++t)
            #pragma unroll
            for (int i = 0; i < 8; ++i) {
                int c = cc*32 + quad*8 + i;
                qf[cc][t][i] = (short)f2b(qb[(size_t)c*NN + t*16 + lrow]);
            }

    const u16* pkb  = pk2 + (size_t)b * (8*MM*8);
    const int  mrw  = w*16 + lrow;                  // K A-frag m-row offset
    const u16* vrow = vt + ((size_t)b*CV + cs*128 + w*16 + lrow)*MM + quad*8;

    floatx4 oacc[4];
    #pragma unroll
    for (int t = 0; t < 4; ++t) oacc[t] = (floatx4){0.f, 0.f, 0.f, 0.f};
    float sacc[4] = {0.f, 0.f, 0.f, 0.f};

    // ---- preamble: loads for iter 0, QK(0) -> P[0]
    bf16x8 k0 = *(const bf16x8*)(pkb + ((size_t)quad*MM + mrw)*8);
    bf16x8 k1 = *(const bf16x8*)(pkb + ((size_t)(quad+4)*MM + mrw)*8);
    bf16x8 vf[4];
    #pragma unroll
    for (int cc = 0; cc < 4; ++cc)
        vf[cc] = *(const bf16x8*)(vrow + cc*32);
    qk_phase(k0, k1, qf, sacc, P[0], lrow, cbw, sw);

    for (int it = 0; it < NIT - 1; ++it) {
        __syncthreads();                            // P[it&1] complete
        const int mb2 = (it + 1) << 7;
        // unconditional prefetch of iter it+1 (latency hides under PV)
        bf16x8 k0n = *(const bf16x8*)(pkb + ((size_t)quad*MM + mb2 + mrw)*8);
        bf16x8 k1n = *(const bf16x8*)(pkb + ((size_t)(quad+4)*MM + mb2 + mrw)*8);
        bf16x8 vn[4];
        #pragma unroll
        for (int cc = 0; cc < 4; ++cc)
            vn[cc] = *(const bf16x8*)(vrow + mb2 + cc*32);
        pv_phase(vf, oacc, P[it & 1], lrow, quad, sw);
        qk_phase(k0n, k1n, qf, sacc, P[(it + 1) & 1], lrow, cbw, sw);
        #pragma unroll
        for (int cc = 0; cc < 4; ++cc) vf[cc] = vn[cc];
    }
    __syncthreads();
    pv_phase(vf, oacc, P[(NIT - 1) & 1], lrow, quad, sw);

    // ---- softmax denominator: quad-reduce, then 8-wave LDS reduce
    #pragma unroll
    for (int t = 0; t < 4; ++t) {
        float v = sacc[t];
        v += __shfl_xor(v, 16, 64);
        v += __shfl_xor(v, 32, 64);
        if (l < 16) sums_s[w][t*16 + l] = v;
    }
    __syncthreads();
    float inv[4];
    #pragma unroll
    for (int t = 0; t < 4; ++t) {
        float d = 0.f;
        #pragma unroll
        for (int w2 = 0; w2 < 8; ++w2) d += sums_s[w2][t*16 + lrow];
        inv[t] = 1.0f / d;
    }

    // ---- normalized direct write: out[b, 256 + cs*128 + c_loc, n0 + n_l]
    float* ob = out + ((size_t)(b*512 + 256 + cs*128))*NN + n0;
    #pragma unroll
    for (int t = 0; t < 4; ++t)
        #pragma unroll
        for (int r = 0; r < 4; ++r) {
            int c_loc = w*16 + quad*4 + r;
            ob[(size_t)c_loc*NN + t*16 + lrow] = oacc[t][r] * inv[t];
        }
}

// ======================= fallback (proven round-4) path =======================

__global__ void pool_v_f32(const float* __restrict__ src, float* __restrict__ out) {
    int e = blockIdx.x * 256 + threadIdx.x;
    int c = e & 255;
    int r = e >> 8;
    int ww = r & 31;  int hh = (r >> 5) & 31;
    int t  = (r >> 10) & 3;  int b = r >> 12;
    int m  = r & (MM - 1);
    const float* s = src + ((size_t)(((b*NT + t)*CV + c)*HH + 2*hh))*WW + 2*ww;
    out[(size_t)b*OUT_B + (size_t)m*CV + c] = fmaxf(fmaxf(s[0], s[1]), fmaxf(s[WW], s[WW+1]));
}

__global__ void pool_k_f32(const float* __restrict__ src, float* __restrict__ dst) {
    int e = blockIdx.x * 256 + threadIdx.x;
    int c = e & 63;
    int r = e >> 6;
    int ww = r & 31;  int hh = (r >> 5) & 31;
    int t  = (r >> 10) & 3;  int b = r >> 12;
    const float* s = src + ((size_t)(((b*NT + t)*CK + c)*HH + 2*hh))*WW + 2*ww;
    dst[e] = fmaxf(fmaxf(s[0], s[1]), fmaxf(s[WW], s[WW+1]));
}

__global__ void copy_qv_f32(const float4* __restrict__ src, float4* __restrict__ dst) {
    int u = blockIdx.x * 256 + threadIdx.x;
    int b  = u >> 18;
    int ru = u & 262143;
    dst[(size_t)b * (OUT_B/4) + ru] = src[u];
}

template<bool STAGED_K>
__launch_bounds__(256)
__global__ void attn_old(const float* __restrict__ pk,
                         const float* __restrict__ mk,
                         const float* __restrict__ qk,
                         float* __restrict__ out) {
    __shared__ __align__(16) float q_lds[CK][4];
    __shared__ __align__(16) float sarr[4][MM];
    __shared__ float inv_l[4];

    const int tid = threadIdx.x;
    const int blk = blockIdx.x;
    const int b   = blk >> 10;
    const int n0  = (blk & 1023) << 2;

    {
        int c = tid >> 2, qi = tid & 3;
        q_lds[c][qi] = qk[((size_t)(b*CK + c))*NN + n0 + qi];
    }
    __syncthreads();

    #pragma unroll
    for (int i = 0; i < 16; ++i) {
        int m = tid + (i << 8);
        float a0 = 0.f, a1 = 0.f, a2 = 0.f, a3 = 0.f;
        if (STAGED_K) {
            const float4* k4 = reinterpret_cast<const float4*>(pk + ((size_t)b*MM + m)*CK);
            #pragma unroll
            for (int cc = 0; cc < 16; ++cc) {
                float4 kv = k4[cc];
                int c = cc*4;
                float4 q0 = *reinterpret_cast<const float4*>(&q_lds[c][0]);
                float4 q1 = *reinterpret_cast<const float4*>(&q_lds[c+1][0]);
                float4 q2 = *reinterpret_cast<const float4*>(&q_lds[c+2][0]);
                float4 q3 = *reinterpret_cast<const float4*>(&q_lds[c+3][0]);
                a0 += kv.x*q0.x + kv.y*q1.x + kv.z*q2.x + kv.w*q3.x;
                a1 += kv.x*q0.y + kv.y*q1.y + kv.z*q2.y + kv.w*q3.y;
                a2 += kv.x*q0.z + kv.y*q1.z + kv.z*q2.z + kv.w*q3.z;
                a3 += kv.x*q0.w + kv.y*q1.w + kv.z*q2.w + kv.w*q3.w;
            }
        } else {
            int ww = m & 31, hh = (m >> 5) & 31, t = m >> 10;
            const float* base = mk + ((size_t)((b*NT + t)*CK)*HH + 2*hh)*WW + 2*ww;
            for (int c = 0; c < CK; ++c) {
                const float* s = base + (size_t)c*HH*WW;
                float kv = fmaxf(fmaxf(s[0], s[1]), fmaxf(s[WW], s[WW+1]));
                float4 q = *reinterpret_cast<const float4*>(&q_lds[c][0]);
                a0 += kv*q.x; a1 += kv*q.y; a2 += kv*q.z; a3 += kv*q.w;
            }
        }
        sarr[0][m] = a0*SCALE;
        sarr[1][m] = a1*SCALE;
        sarr[2][m] = a2*SCALE;
        sarr[3][m] = a3*SCALE;
    }
    __syncthreads();

    const int wave = tid >> 6, lane = tid & 63;
    float mx = -3.0e38f;
    for (int m = lane; m < MM; m += 64) mx = fmaxf(mx, sarr[wave][m]);
    #pragma unroll
    for (int off = 32; off > 0; off >>= 1) mx = fmaxf(mx, __shfl_xor(mx, off, 64));
    float ls = 0.f;
    for (int m = lane; m < MM; m += 64) {
        float p = __expf(sarr[wave][m] - mx);
        sarr[wave][m] = p;
        ls += p;
    }
    #pragma unroll
    for (int off = 32; off > 0; off >>= 1) ls += __shfl_xor(ls, off, 64);
    if (lane == 0) inv_l[wave] = 1.0f / ls;
    __syncthreads();

    const int c4 = lane;
    const float4* vb = reinterpret_cast<const float4*>(out + (size_t)b*OUT_B) + c4;
    const float* prow = sarr[wave];
    float a0 = 0.f, a1 = 0.f, a2 = 0.f, a3 = 0.f;
    for (int m = 0; m < MM; m += 4) {
        float4 p4 = *reinterpret_cast<const float4*>(prow + m);
        const float4* vp = vb + (size_t)m*(CV/4);
        float4 v0 = vp[0], v1 = vp[CV/4], v2 = vp[CV/2], v3 = vp[3*(CV/4)];
        a0 += p4.x*v0.x + p4.y*v1.x + p4.z*v2.x + p4.w*v3.x;
        a1 += p4.x*v0.y + p4.y*v1.y + p4.z*v2.y + p4.w*v3.y;
        a2 += p4.x*v0.z + p4.y*v1.z + p4.z*v2.z + p4.w*v3.z;
        a3 += p4.x*v0.w + p4.y*v1.w + p4.z*v2.w + p4.w*v3.w;
    }

    float inv = inv_l[wave];
    int n = n0 + wave;
    size_t ob = ((size_t)(b*512 + 256 + c4*4))*NN + n;
    out[ob]        = a0*inv;
    out[ob + NN]   = a1*inv;
    out[ob + 2*NN] = a2*inv;
    out[ob + 3*NN] = a3*inv;
}

// ================================ launcher ================================

extern "C" void kernel_launch(void* const* d_in, const int* in_sizes, int n_in,
                              void* d_out, int out_size, void* d_ws, size_t ws_size,
                              hipStream_t stream) {
    const float* mk = (const float*)d_in[0];
    const float* mv = (const float*)d_in[1];
    const float* qk = (const float*)d_in[2];
    const float* qv = (const float*)d_in[3];
    float* out = (float*)d_out;

    // fast-path ws layout: pk2 1MB | vt 4MB  (5 MB total)
    u16* pk2 = (u16*)d_ws;
    u16* vt  = pk2 + (size_t)NB*8*MM*8;                 // 524288 u16
    const size_t need = ((size_t)NB*8*MM*8 + (size_t)NB*CV*MM) * sizeof(u16);

    if (ws_size >= need) {
        prep<<<PRE_T/256, 256, 0, stream>>>(mk, mv, (const float4*)qv, pk2, vt, out);
        attn_v3<<<256, 512, 0, stream>>>(pk2, vt, qk, out);
    } else {
        const size_t pk_bytes = (size_t)NB*MM*CK*sizeof(float);
        const bool staged = (ws_size >= pk_bytes);
        float* pk = (float*)d_ws;
        pool_v_f32<<<(NB*MM*CV)/256, 256, 0, stream>>>(mv, out);
        if (staged) {
            pool_k_f32<<<(NB*MM*CK)/256, 256, 0, stream>>>(mk, pk);
            attn_old<true ><<<NB*(NN/4), 256, 0, stream>>>(pk, mk, qk, out);
        } else {
            attn_old<false><<<NB*(NN/4), 256, 0, stream>>>(pk, mk, qk, out);
        }
        copy_qv_f32<<<((NB*CV*HH*WW)/4)/256, 256, 0, stream>>>((const float4*)qv, (float4*)out);
    }
}